// Round 7
// baseline (1325.305 us; speedup 1.0000x reference)
//
#include <hip/hip_runtime.h>
#include <hip/hip_bf16.h>
#include <math.h>

#define NND 100000   // nodes
#define EE  200000   // edges
#define LL  3        // layers
#define DD  300      // node dim
#define HH  150      // per-direction message dim

#define MPAD 100096  // 391 * 256
#define KP   320     // K padded (multiple of 32)
#define NPJ  640     // proj N padded
#define NUP  384     // update N padded
#define NTK  (KP / 32)

#define NB   49          // scan blocks (2048 elems each)
#define SCN  (NB * 2048) // 100352 >= MPAD+1

// GEMM tile geometry: BM=256, BN=128, BK=32; 4 waves, wave-tile 128x64
#define BUFSZ 24576      // (256 + 128) * 32 * 2B per K-tile
#define BSTRIDE 132      // padded fp32 bounce row stride

typedef __attribute__((ext_vector_type(8))) short bf16x8;
typedef __attribute__((ext_vector_type(4))) short bf16x4;
typedef __attribute__((ext_vector_type(4))) float f32x4;

__device__ __forceinline__ float gelu_exact(float z) {
    return 0.5f * z * (1.0f + erff(z * 0.7071067811865475f));
}
__device__ __forceinline__ unsigned short f2bf(float f) {
    union { float fv; unsigned u; } v; v.fv = f;
    unsigned r = v.u + 0x7fff + ((v.u >> 16) & 1);   // RNE (finite inputs)
    return (unsigned short)(r >> 16);
}
__device__ __forceinline__ float bf2f(unsigned short b) {
    union { unsigned u; float fv; } v; v.u = ((unsigned)b) << 16;
    return v.fv;
}

// ---------------- weight packing ----------------
__global__ __launch_bounds__(256) void pack_w(
    const float* __restrict__ Wr, const float* __restrict__ Wc,
    const float* __restrict__ Wa,
    unsigned short* __restrict__ Bt, unsigned short* __restrict__ Wat)
{
    int i = blockIdx.x * 256 + threadIdx.x;
    const int btTotal = LL * NPJ * KP;
    if (i < btTotal) {
        int l = i / (NPJ * KP);
        int rem = i % (NPJ * KP);
        int n = rem / KP;
        int k = rem % KP;
        float v = 0.f;
        if (k < DD && n < 600) {
            const float* W = (n < 300) ? Wr : Wc;
            int nn = (n < 300) ? n : n - 300;
            int krow = (nn < 150) ? k : 300 + k;
            int j    = (nn < 150) ? nn : nn - 150;
            v = W[(size_t)l * 600 * 150 + (size_t)krow * 150 + j];
        }
        Bt[i] = f2bf(v);
    } else {
        int i2 = i - btTotal;
        if (i2 < NUP * KP) {
            int n = i2 / KP, k = i2 % KP;
            float v = (n < DD && k < DD) ? Wa[(size_t)k * DD + n] : 0.f;
            Wat[i2] = f2bf(v);
        }
    }
}

// vbf[MPAD][KP] = bf16(x), zero pads
__global__ __launch_bounds__(256) void init_vbf(
    const float* __restrict__ x, unsigned short* __restrict__ vbf)
{
    int idx = blockIdx.x * 256 + threadIdx.x;       // chunk of 8
    int row = idx / (KP / 8);
    int gk  = (idx % (KP / 8)) * 8;
    if (row >= MPAD) return;
    unsigned short tmp[8];
    if (row < NND && gk < DD) {
        if (gk + 8 <= DD) {
            const float4* p = (const float4*)(x + (size_t)row * DD + gk);
            float4 f0 = p[0], f1 = p[1];
            tmp[0] = f2bf(f0.x); tmp[1] = f2bf(f0.y);
            tmp[2] = f2bf(f0.z); tmp[3] = f2bf(f0.w);
            tmp[4] = f2bf(f1.x); tmp[5] = f2bf(f1.y);
            tmp[6] = f2bf(f1.z); tmp[7] = f2bf(f1.w);
        } else {
            #pragma unroll
            for (int j = 0; j < 8; ++j)
                tmp[j] = (gk + j < DD) ? f2bf(x[(size_t)row * DD + gk + j]) : 0;
        }
    } else {
        #pragma unroll
        for (int j = 0; j < 8; ++j) tmp[j] = 0;
    }
    *((bf16x8*)&vbf[(size_t)row * KP + gk]) = *((bf16x8*)tmp);
}

// ---------------- CSR build ----------------
__global__ __launch_bounds__(256) void hist_deg(
    const int* __restrict__ src, const int* __restrict__ dst,
    int* __restrict__ deg)
{
    int e = blockIdx.x * 256 + threadIdx.x;
    if (e >= EE) return;
    atomicAdd(&deg[dst[e]], 1);
    atomicAdd(&deg[SCN + src[e]], 1);
}

__global__ __launch_bounds__(256) void scanA(
    const int* __restrict__ deg, int* __restrict__ off, int* __restrict__ bsum)
{
    __shared__ int ls[256];
    const int t = threadIdx.x, row = blockIdx.y;
    const int base = blockIdx.x * 2048 + t * 8;
    const int* dg = deg + (size_t)row * SCN + base;
    int v[8];
    #pragma unroll
    for (int j = 0; j < 8; ++j) v[j] = dg[j];
    int tot = 0;
    #pragma unroll
    for (int j = 0; j < 8; ++j) tot += v[j];
    ls[t] = tot;
    __syncthreads();
    #pragma unroll
    for (int d = 1; d < 256; d <<= 1) {
        int tv = (t >= d) ? ls[t - d] : 0;
        __syncthreads();
        ls[t] += tv;
        __syncthreads();
    }
    int run = ls[t] - tot;
    int* op = off + (size_t)row * SCN + base;
    #pragma unroll
    for (int j = 0; j < 8; ++j) { op[j] = run; run += v[j]; }
    if (t == 255) bsum[row * 64 + blockIdx.x] = ls[255];
}

__global__ __launch_bounds__(256) void scanB(int* __restrict__ bsum)
{
    if (threadIdx.x < 2) {
        int row = threadIdx.x, c = 0;
        for (int i = 0; i < NB; ++i) {
            int tv = bsum[row * 64 + i];
            bsum[row * 64 + i] = c;
            c += tv;
        }
    }
}

__global__ __launch_bounds__(256) void scanC(
    int* __restrict__ off, const int* __restrict__ bsum, int* __restrict__ cur)
{
    const int t = threadIdx.x, row = blockIdx.y;
    const int base = blockIdx.x * 2048 + t * 8;
    const int add = bsum[row * 64 + blockIdx.x];
    int* op = off + (size_t)row * SCN + base;
    int* cp = cur + (size_t)row * SCN + base;
    #pragma unroll
    for (int j = 0; j < 8; ++j) {
        int v = op[j] + add;
        op[j] = v;
        cp[j] = v;
    }
}

__global__ __launch_bounds__(256) void fill_adj(
    const int* __restrict__ src, const int* __restrict__ dst,
    int* __restrict__ cur, int* __restrict__ adj)
{
    int e = blockIdx.x * 256 + threadIdx.x;
    if (e >= EE) return;
    int s = src[e], d = dst[e];
    int pd = atomicAdd(&cur[d], 1);
    adj[pd] = s;
    int ps = atomicAdd(&cur[SCN + s], 1);
    adj[EE + ps] = d;
}

// ---------------- aggregation (no atomics) ----------------
__global__ __launch_bounds__(256) void aggregate(
    const int* __restrict__ off, const int* __restrict__ adj,
    const unsigned short* __restrict__ P,
    const float* __restrict__ br, const float* __restrict__ bc,
    unsigned short* __restrict__ RC)
{
    const int n    = blockIdx.x * 4 + (threadIdx.x >> 6);
    const int dir  = blockIdx.y;
    const int lane = threadIdx.x & 63;
    const int h0 = lane, h1 = lane + 64, h2 = lane + 128;

    unsigned short* outrow = RC + (size_t)n * KP + dir * 150;
    if (n >= NND) {
        outrow[h0] = 0; outrow[h1] = 0;
        if (h2 < (dir ? 170 : 150)) outrow[h2] = 0;
        return;
    }

    const int* offp = off + (size_t)dir * SCN;
    const int* adjp = adj + (size_t)dir * EE;
    const float* bias = dir ? bc : br;
    const unsigned short* own = P + (size_t)n * NPJ + dir * 300;
    const int poff = dir ? 450 : 150;

    float o0 = bf2f(own[h0]) + bias[h0];
    float o1 = bf2f(own[h1]) + bias[h1];
    float o2 = (h2 < 150) ? bf2f(own[h2]) + bias[h2] : 0.f;

    float s0 = 0.f, s1 = 0.f, s2 = 0.f;
    int beg = offp[n], end = offp[n + 1];
    for (int i = beg; i < end; ++i) {
        const unsigned short* pp = P + (size_t)adjp[i] * NPJ + poff;
        s0 += gelu_exact(o0 + bf2f(pp[h0]));
        s1 += gelu_exact(o1 + bf2f(pp[h1]));
        if (h2 < 150) s2 += gelu_exact(o2 + bf2f(pp[h2]));
    }
    outrow[h0] = f2bf(s0);
    outrow[h1] = f2bf(s1);
    if (h2 < 150)                  outrow[h2] = f2bf(s2);
    else if (dir == 1 && h2 < 170) outrow[h2] = 0;
}

// ---------------- MFMA GEMM: BM=256, BN=128, BK=32, 4 waves (128x64 each) ----
#define GLOAD16(gp, lp) __builtin_amdgcn_global_load_lds( \
    (const __attribute__((address_space(1))) unsigned int*)(gp), \
    (__attribute__((address_space(3))) unsigned int*)(lp), 16, 0, 0)

// A tile 256x32: 1024 chunks of 16B; 4 per thread
#define STAGE_A(dstp, srcbase, rowoff, k0) do {                              \
    _Pragma("unroll")                                                        \
    for (int i_ = 0; i_ < 4; ++i_) {                                         \
        int cb_ = wid * 256 + i_ * 64;                                       \
        int ci_ = cb_ + lane;                                                \
        int row_ = ci_ >> 2, pc_ = ci_ & 3;                                  \
        int c_ = pc_ ^ ((row_ >> 1) & 3);                                    \
        GLOAD16(srcbase + (size_t)(rowoff + row_) * KP + (k0) + c_ * 8,      \
                &(dstp)[cb_ * 8]);                                           \
    } } while (0)

// B tile 128x32: 512 chunks; 2 per thread
#define STAGE_B(dstp, srcbase, rowoff, k0) do {                              \
    _Pragma("unroll")                                                        \
    for (int i_ = 0; i_ < 2; ++i_) {                                         \
        int cb_ = wid * 128 + i_ * 64;                                       \
        int ci_ = cb_ + lane;                                                \
        int row_ = ci_ >> 2, pc_ = ci_ & 3;                                  \
        int c_ = pc_ ^ ((row_ >> 1) & 3);                                    \
        GLOAD16(srcbase + (size_t)(rowoff + row_) * KP + (k0) + c_ * 8,      \
                &(dstp)[cb_ * 8]);                                           \
    } } while (0)

// C[256x128 tiles] = A[M,KP](bf16) @ Bt[N,KP]^T(bf16)
// MODE 0: P[row*NPJ+col] = bf16(acc)
// MODE 1: nv = vbf_old + gelu(acc + bias[col]); last? out=fp32(nv) : vbf=bf16(nv)
template<int MODE>
__global__ __launch_bounds__(256) void gemm_mfma(
    const unsigned short* __restrict__ Ab,
    const unsigned short* __restrict__ Bt,
    unsigned short* __restrict__ P,
    float* __restrict__ outv, unsigned short* __restrict__ vbf,
    const float* __restrict__ bias, int last)
{
    __shared__ char smem[3 * BUFSZ];   // 72 KB: 3 x (A 16KB + B 8KB)
    float* bounce = (float*)smem;      // 64 x BSTRIDE fp32, reused after K-loop

    const int tid  = threadIdx.x;
    const int lane = tid & 63;
    const int wid  = tid >> 6;

    // bijective XCD swizzle (m204)
    const int gx   = gridDim.x;
    const int nwg  = gx * gridDim.y;
    const int flat = blockIdx.y * gx + blockIdx.x;
    const int q = nwg >> 3, r = nwg & 7;
    const int xcd = flat & 7, off = flat >> 3;
    const int lid = (xcd < r ? xcd * (q + 1) : r * (q + 1) + (xcd - r) * q) + off;
    const int brow = (lid / gx) * 256;
    const int bcol = (lid % gx) * 128;

    const int wr = wid >> 1;           // 0..1 row half (128 rows)
    const int wc = wid & 1;            // 0..1 col half (64 cols)

    f32x4 acc[8][4];
    #pragma unroll
    for (int i = 0; i < 8; ++i)
        #pragma unroll
        for (int j = 0; j < 4; ++j)
            #pragma unroll
            for (int rr = 0; rr < 4; ++rr) acc[i][j][rr] = 0.f;

    // prologue: stage tiles 0 and 1 (6 vmem ops per wave per tile)
    #pragma unroll
    for (int t = 0; t < 2; ++t) {
        unsigned short* Al = (unsigned short*)(smem + t * BUFSZ);
        unsigned short* Bl = (unsigned short*)(smem + t * BUFSZ + 16384);
        STAGE_A(Al, Ab, brow, t * 32);
        STAGE_B(Bl, Bt, bcol, t * 32);
    }

    #pragma unroll
    for (int t = 0; t < NTK; ++t) {
        const int b  = t % 3;
        unsigned short* Alc = (unsigned short*)(smem + b * BUFSZ);
        unsigned short* Blc = (unsigned short*)(smem + b * BUFSZ + 16384);
        if (t + 2 < NTK) {
            const int bn = (t + 2) % 3;
            unsigned short* Aln = (unsigned short*)(smem + bn * BUFSZ);
            unsigned short* Bln = (unsigned short*)(smem + bn * BUFSZ + 16384);
            STAGE_A(Aln, Ab, brow, (t + 2) * 32);
            STAGE_B(Bln, Bt, bcol, (t + 2) * 32);
            // tile t's 6 loads done; tiles t+1,t+2 (12) stay in flight
            asm volatile("s_waitcnt vmcnt(12)" ::: "memory");
        } else if (t + 1 < NTK) {
            asm volatile("s_waitcnt vmcnt(6)" ::: "memory");
        } else {
            asm volatile("s_waitcnt vmcnt(0)" ::: "memory");
        }
        __builtin_amdgcn_s_barrier();

        bf16x8 af[8], bfr[4];
        #pragma unroll
        for (int mi = 0; mi < 8; ++mi) {
            int row = wr * 128 + mi * 16 + (lane & 15);
            af[mi] = *((const bf16x8*)&Alc[row * 32 + (((lane >> 4) ^ ((row >> 1) & 3)) * 8)]);
        }
        #pragma unroll
        for (int nj = 0; nj < 4; ++nj) {
            int row = wc * 64 + nj * 16 + (lane & 15);
            bfr[nj] = *((const bf16x8*)&Blc[row * 32 + (((lane >> 4) ^ ((row >> 1) & 3)) * 8)]);
        }
        __builtin_amdgcn_s_setprio(1);
        #pragma unroll
        for (int mi = 0; mi < 8; ++mi)
            #pragma unroll
            for (int nj = 0; nj < 4; ++nj)
                acc[mi][nj] = __builtin_amdgcn_mfma_f32_16x16x32_bf16(
                    af[mi], bfr[nj], acc[mi][nj], 0, 0, 0);
        __builtin_amdgcn_s_setprio(0);
        __builtin_amdgcn_s_barrier();   // protect buf before re-stage
    }

    // ---- coalesced epilogue via fp32 LDS bounce (four 64-row quarters) ----
    const int ro = tid >> 5;          // 0..7
    const int co = (tid & 31) * 4;    // 0..124
    #pragma unroll
    for (int qtr = 0; qtr < 4; ++qtr) {
        if (wr == (qtr >> 1)) {
            const int mib = (qtr & 1) * 4;
            #pragma unroll
            for (int mi = 0; mi < 4; ++mi)
                #pragma unroll
                for (int nj = 0; nj < 4; ++nj) {
                    int lcol = wc * 64 + nj * 16 + (lane & 15);
                    int rb = mi * 16 + ((lane >> 4) << 2);
                    #pragma unroll
                    for (int rr = 0; rr < 4; ++rr)
                        bounce[(rb + rr) * BSTRIDE + lcol] = acc[mib + mi][nj][rr];
                }
        }
        __syncthreads();
        #pragma unroll
        for (int i = 0; i < 8; ++i) {
            int lrow = ro + i * 8;
            int grow = brow + qtr * 64 + lrow;
            float4 vv = *(const float4*)&bounce[lrow * BSTRIDE + co];
            if (MODE == 0) {
                bf16x4 o;
                o[0] = (short)f2bf(vv.x); o[1] = (short)f2bf(vv.y);
                o[2] = (short)f2bf(vv.z); o[3] = (short)f2bf(vv.w);
                *((bf16x4*)&P[(size_t)grow * NPJ + bcol + co]) = o;
            } else if (grow < NND) {
                int gc = bcol + co;
                if (bcol < 256) {   // uniform: all 4 cols < 300
                    float4 bv = *(const float4*)&bias[gc];
                    bf16x4 old = *(const bf16x4*)&vbf[(size_t)grow * KP + gc];
                    float4 nv;
                    nv.x = bf2f((unsigned short)old[0]) + gelu_exact(vv.x + bv.x);
                    nv.y = bf2f((unsigned short)old[1]) + gelu_exact(vv.y + bv.y);
                    nv.z = bf2f((unsigned short)old[2]) + gelu_exact(vv.z + bv.z);
                    nv.w = bf2f((unsigned short)old[3]) + gelu_exact(vv.w + bv.w);
                    if (last) {
                        *((float4*)&outv[(size_t)grow * DD + gc]) = nv;
                    } else {
                        bf16x4 o;
                        o[0] = (short)f2bf(nv.x); o[1] = (short)f2bf(nv.y);
                        o[2] = (short)f2bf(nv.z); o[3] = (short)f2bf(nv.w);
                        *((bf16x4*)&vbf[(size_t)grow * KP + gc]) = o;
                    }
                } else {
                    #pragma unroll
                    for (int j = 0; j < 4; ++j) {
                        int c = gc + j;
                        if (c < DD) {
                            float vj = (j == 0) ? vv.x : (j == 1) ? vv.y
                                     : (j == 2) ? vv.z : vv.w;
                            size_t vidx = (size_t)grow * KP + c;
                            float nv = bf2f(vbf[vidx]) + gelu_exact(vj + bias[c]);
                            if (last) outv[(size_t)grow * DD + c] = nv;
                            else      vbf[vidx] = f2bf(nv);
                        }
                    }
                }
            }
        }
        __syncthreads();
    }
}

extern "C" void kernel_launch(void* const* d_in, const int* in_sizes, int n_in,
                              void* d_out, int out_size, void* d_ws, size_t ws_size,
                              hipStream_t stream) {
    const float* x  = (const float*)d_in[0];
    const int*   ei = (const int*)  d_in[1];
    const float* Wr = (const float*)d_in[2];
    const float* br = (const float*)d_in[3];
    const float* Wc = (const float*)d_in[4];
    const float* bc = (const float*)d_in[5];
    const float* Wa = (const float*)d_in[6];
    const float* ba = (const float*)d_in[7];
    float* out = (float*)d_out;

    const size_t P_elems   = (size_t)MPAD * NPJ;   // bf16
    const size_t RC_elems  = (size_t)MPAD * KP;    // bf16
    const size_t V_elems   = (size_t)MPAD * KP;    // bf16
    const size_t Bt_elems  = (size_t)LL * NPJ * KP;
    const size_t Wat_elems = (size_t)NUP * KP;

    unsigned short* P   = (unsigned short*)d_ws;
    unsigned short* RC  = P + P_elems;
    unsigned short* vbf = RC + RC_elems;
    unsigned short* Bt  = vbf + V_elems;
    unsigned short* Wat = Bt + Bt_elems;
    int* deg  = (int*)(Wat + Wat_elems);
    int* off  = deg + 2 * SCN;
    int* curp = off + 2 * SCN;
    int* adj  = curp + 2 * SCN;
    int* bsum = adj + 2 * EE;
    const size_t need = (char*)(bsum + 128) - (char*)d_ws;
    if (ws_size < need) return;  // visible fail (output stays poisoned)

    pack_w<<<2880, 256, 0, stream>>>(Wr, Wc, Wa, Bt, Wat);
    init_vbf<<<(int)((V_elems / 8 + 255) / 256), 256, 0, stream>>>(x, vbf);

    const int* src = ei;
    const int* dst = ei + EE;

    hipMemsetAsync(deg, 0, 2 * SCN * sizeof(int), stream);
    hist_deg<<<(EE + 255) / 256, 256, 0, stream>>>(src, dst, deg);
    scanA<<<dim3(NB, 2), 256, 0, stream>>>(deg, off, bsum);
    scanB<<<1, 256, 0, stream>>>(bsum);
    scanC<<<dim3(NB, 2), 256, 0, stream>>>(off, bsum, curp);
    fill_adj<<<(EE + 255) / 256, 256, 0, stream>>>(src, dst, curp, adj);

    dim3 gproj(NPJ / 128, MPAD / 256);
    dim3 gupd (NUP / 128, MPAD / 256);
    dim3 gagg (MPAD / 4, 2);

    for (int l = 0; l < LL; ++l) {
        gemm_mfma<0><<<gproj, 256, 0, stream>>>(
            vbf, Bt + (size_t)l * NPJ * KP, P, nullptr, nullptr, nullptr, 0);
        aggregate<<<gagg, 256, 0, stream>>>(
            off, adj, P, br + (size_t)l * HH, bc + (size_t)l * HH, RC);
        gemm_mfma<1><<<gupd, 256, 0, stream>>>(
            RC, Wat, nullptr, out, vbf, ba, (l == LL - 1) ? 1 : 0);
    }
}